// Round 1
// baseline (98.451 us; speedup 1.0000x reference)
//
#include <hip/hip_runtime.h>
#include <math.h>

#define EPSQ 1e-8f
#define LOG2E 1.4426950408889634f

typedef float f2 __attribute__((ext_vector_type(2)));
typedef float f4 __attribute__((ext_vector_type(4)));

__device__ __forceinline__ float rcp_fast(float x) { return __builtin_amdgcn_rcpf(x); }
__device__ __forceinline__ float rsq_fast(float x) { return __builtin_amdgcn_rsqf(x); }
__device__ __forceinline__ f2 pk_fma(f2 a, f2 b, f2 c) { return __builtin_elementwise_fma(a, b, c); }

// DPP cross-lane move: ctrl must be a compile-time constant.
#define DPP_F(x, ctrl) \
    __int_as_float(__builtin_amdgcn_update_dpp(0, __float_as_int(x), (ctrl), 0xF, 0xF, true))

// All-reduce sum within each aligned 16-lane group (pure VALU, no LDS).
__device__ __forceinline__ float allsum16(float v) {
    v += DPP_F(v, 0xB1);   // quad_perm [1,0,3,2]  == xor 1
    v += DPP_F(v, 0x4E);   // quad_perm [2,3,0,1]  == xor 2
    v += DPP_F(v, 0x124);  // row_ror:4
    v += DPP_F(v, 0x128);  // row_ror:8
    return v;
}

// Hamilton product (q * x) + t as EXACTLY 8 v_pk_fma_f32: all broadcasts,
// swaps, and sign patterns live in VOP3P op_sel/neg modifiers, so the
// compiler cannot expand them into v_mov/v_xor operand-prep.
//   q01=(w,x) q23=(y,z)  p01=(xw,xx) p23=(xy,xz)  ta=(0,tx) tb=(ty,tz)
//   a  = (vote.w, vote.x+tx)   b2 = (vote.y+ty, vote.z+tz)
__device__ __forceinline__ void hamilton_pk(f2 q01, f2 q23, f2 p01, f2 p23,
                                            f2 ta, f2 tb, f2& a, f2& b2) {
    asm("v_pk_fma_f32 %0, %2, %3, %4 op_sel:[0,0,0] op_sel_hi:[0,1,1]\n\t"                           // a  = (w,w)*(xw,xx) + ta
        "v_pk_fma_f32 %0, %2, %3, %0 op_sel:[1,1,0] op_sel_hi:[1,0,1] neg_lo:[1,0,0]\n\t"            // a += (-x,x)*(xx,xw)
        "v_pk_fma_f32 %0, %5, %6, %0 op_sel:[0,0,0] op_sel_hi:[0,1,1] neg_lo:[1,0,0]\n\t"            // a += (-y,y)*(xy,xz)
        "v_pk_fma_f32 %0, %5, %6, %0 op_sel:[1,1,0] op_sel_hi:[1,0,1] neg_lo:[1,0,0] neg_hi:[1,0,0]\n\t" // a += (-z,-z)*(xz,xy)
        "v_pk_fma_f32 %1, %2, %6, %7 op_sel:[0,0,0] op_sel_hi:[0,1,1]\n\t"                           // b  = (w,w)*(xy,xz) + tb
        "v_pk_fma_f32 %1, %2, %6, %1 op_sel:[1,1,0] op_sel_hi:[1,0,1] neg_lo:[1,0,0]\n\t"            // b += (-x,x)*(xz,xy)
        "v_pk_fma_f32 %1, %5, %3, %1 op_sel:[0,0,0] op_sel_hi:[0,1,1] neg_hi:[1,0,0]\n\t"            // b += (y,-y)*(xw,xx)
        "v_pk_fma_f32 %1, %5, %3, %1 op_sel:[1,1,0] op_sel_hi:[1,0,1]"                               // b += (z,z)*(xx,xw)
        : "=&v"(a), "=&v"(b2)
        : "v"(q01), "v"(p01), "v"(ta), "v"(q23), "v"(p23), "v"(tb));
}

// One thread per (o, TWO samples nA/nB). Block = 256 = 16 lane-rows x 16 o.
// tid = ln*16 + o (o in low 4 bits): softmax-over-o lives in one 16-lane DPP row.
// Two samples per thread double the independent latency chains (exp2 -> 4xDPP
// -> rcp is ~70 cyc of pure latency; ILP, not TLP, is the cheap cover for it),
// and amortize param/LDS/epilogue work 2x. launch_bounds(256,2) lifts the
// VGPR cap to 256 so both vote sets (128 VGPRs) stay resident without spill.
__global__ __launch_bounds__(256, 2) void caps_kernel(
    const float* __restrict__ x,      // [N,16,4]
    const float* __restrict__ quats,  // [16,16,4]
    const float* __restrict__ scale,  // [16,16,1]
    const float* __restrict__ trans,  // [16,16,3]
    const float* __restrict__ bias,   // [16]
    const float* __restrict__ beta,   // [16]
    const float* __restrict__ alpha,  // [16]
    float* __restrict__ out)          // [N,16,4]
{
    __shared__ __align__(16) float qs[16][16][4];  // folded scale * qn  [i][o][4]
    __shared__ __align__(16) float tr[16][16][4];  // (0, tx, ty, tz)    [i][o][4]
    __shared__ __align__(16) float xs[32][68];     // x tile (32 samples), +4 float row pad

    const int tid = threadIdx.x;
    const int o   = tid & 15;
    const int ln  = tid >> 4;

    // ---- stage params (o2 in low bits: LDS write addrs 16B apart within a
    // 16-lane group -> 2-way bank aliasing (free), vs 16-way for i2-major).
    {
        const int o2 = tid & 15, i2 = tid >> 4;
        const int pidx = o2 * 16 + i2;                    // [o2][i2] entry
        const float4 q = ((const float4*)quats)[pidx];
        const float sc = scale[pidx];
        const float qn2 = q.x*q.x + q.y*q.y + q.z*q.z + q.w*q.w;
        const float f = sc * rsq_fast(qn2 + EPSQ);
        qs[i2][o2][0] = q.x * f;
        qs[i2][o2][1] = q.y * f;
        qs[i2][o2][2] = q.z * f;
        qs[i2][o2][3] = q.w * f;
        tr[i2][o2][0] = 0.0f;                 // real part untranslated
        tr[i2][o2][1] = trans[pidx*3 + 0];
        tr[i2][o2][2] = trans[pidx*3 + 1];
        tr[i2][o2][3] = trans[pidx*3 + 2];
    }
    // ---- stage x tile: 2048 contiguous floats, two float4 per thread ----
    {
        const size_t base = (size_t)blockIdx.x * 512 + tid;
        const float4 xa = ((const float4*)x)[base];
        const float4 xb = ((const float4*)x)[base + 256];
        *(float4*)&xs[tid >> 4][(tid & 15) * 4]        = xa;
        *(float4*)&xs[(tid >> 4) + 16][(tid & 15) * 4] = xb;
    }
    __syncthreads();

    // ---- votes[i] = (scale*qn) (x) x[n,i] + trans for BOTH samples -------
    f2 vAwx[16], vAyz[16], vBwx[16], vByz[16];
    #pragma unroll
    for (int i = 0; i < 16; ++i) {
        const f4 q4 = *(const f4*)&qs[i][o][0];
        const f4 t4 = *(const f4*)&tr[i][o][0];
        const f4 xa = *(const f4*)&xs[ln][i * 4];
        const f4 xb = *(const f4*)&xs[ln + 16][i * 4];
        hamilton_pk(q4.lo, q4.hi, xa.lo, xa.hi, t4.lo, t4.hi, vAwx[i], vAyz[i]);
        hamilton_pk(q4.lo, q4.hi, xb.lo, xb.hi, t4.lo, t4.hi, vBwx[i], vByz[i]);
    }

    // Running log2-domain logit generator: b_i = dot(vl, votes_i), where
    // vl = log2e*v0 (iter 1), log2e*(v0+v1) (iter 2).
    f2 vlAwx, vlAyz, v0Awx, v0Ayz;
    f2 vlBwx, vlByz, v0Bwx, v0Byz;

    // ---- routing iter 0: b==0 -> uniform c=1/16, folded into squash ----
    {
        f2 uAwx = f2{0.f, 0.f}, uAyz = f2{0.f, 0.f};
        f2 uBwx = f2{0.f, 0.f}, uByz = f2{0.f, 0.f};
        #pragma unroll
        for (int i = 0; i < 16; ++i) {
            uAwx += vAwx[i]; uAyz += vAyz[i];
            uBwx += vBwx[i]; uByz += vByz[i];
        }
        f2 dA = uAwx * uAwx; dA = pk_fma(uAyz, uAyz, dA);
        f2 dB = uBwx * uBwx; dB = pk_fma(uByz, uByz, dB);
        const float n2A = (dA.x + dA.y) * (1.0f / 256.0f);
        const float n2B = (dB.x + dB.y) * (1.0f / 256.0f);
        const float fqA = n2A * rcp_fast(1.f + n2A) * rsq_fast(n2A + EPSQ) * 0.0625f;
        const float fqB = n2B * rcp_fast(1.f + n2B) * rsq_fast(n2B + EPSQ) * 0.0625f;
        v0Awx = uAwx * fqA; v0Ayz = uAyz * fqA;
        v0Bwx = uBwx * fqB; v0Byz = uByz * fqB;
        vlAwx = v0Awx * LOG2E; vlAyz = v0Ayz * LOG2E;
        vlBwx = v0Bwx * LOG2E; vlByz = v0Byz * LOG2E;
    }

    // ---- routing iters 1..2: softmax over o via DPP all-reduce.
    // Max-subtraction dropped: |b_log2| bounded -> exp2 never overflows fp32.
    f2 sAwx, sAyz, oAwx, oAyz;
    f2 sBwx, sByz, oBwx, oByz;
    #pragma unroll
    for (int it = 1; it < 3; ++it) {
        f2 snAwx = f2{0.f, 0.f}, snAyz = f2{0.f, 0.f};
        f2 snBwx = f2{0.f, 0.f}, snByz = f2{0.f, 0.f};
        #pragma unroll
        for (int i = 0; i < 16; ++i) {
            f2 dA = vlAwx * vAwx[i];
            f2 dB = vlBwx * vBwx[i];
            dA = pk_fma(vlAyz, vAyz[i], dA);
            dB = pk_fma(vlByz, vByz[i], dB);
            const float eA  = __builtin_amdgcn_exp2f(dA.x + dA.y);
            const float eB  = __builtin_amdgcn_exp2f(dB.x + dB.y);
            const float seA = allsum16(eA);
            const float seB = allsum16(eB);
            const float cA  = eA * rcp_fast(seA);
            const float cB  = eB * rcp_fast(seB);
            snAwx = pk_fma(f2{cA, cA}, vAwx[i], snAwx);
            snAyz = pk_fma(f2{cA, cA}, vAyz[i], snAyz);
            snBwx = pk_fma(f2{cB, cB}, vBwx[i], snBwx);
            snByz = pk_fma(f2{cB, cB}, vByz[i], snByz);
        }
        sAwx = snAwx; sAyz = snAyz;
        sBwx = snBwx; sByz = snByz;
        const float n2A = snAwx.x*snAwx.x + snAwx.y*snAwx.y + snAyz.x*snAyz.x + snAyz.y*snAyz.y;
        const float n2B = snBwx.x*snBwx.x + snBwx.y*snBwx.y + snByz.x*snByz.x + snByz.y*snByz.y;
        const float fqA = n2A * rcp_fast(1.f + n2A) * rsq_fast(n2A + EPSQ);
        const float fqB = n2B * rcp_fast(1.f + n2B) * rsq_fast(n2B + EPSQ);
        oAwx = snAwx * fqA; oAyz = snAyz * fqA;
        oBwx = snBwx * fqB; oByz = snByz * fqB;
        if (it == 1) {   // generator for iter 2: log2e * (v0 + v1)
            vlAwx = (v0Awx + oAwx) * LOG2E;
            vlAyz = (v0Ayz + oAyz) * LOG2E;
            vlBwx = (v0Bwx + oBwx) * LOG2E;
            vlByz = (v0Byz + oByz) * LOG2E;
        }
    }

    // ---- activation + store (coalesced float4 per thread, both samples) ----
    const float bo = beta[o], ao = alpha[o], bi = bias[o];
    const float n2fA = sAwx.x*sAwx.x + sAwx.y*sAwx.y + sAyz.x*sAyz.x + sAyz.y*sAyz.y;
    const float n2fB = sBwx.x*sBwx.x + sBwx.y*sBwx.y + sByz.x*sByz.x + sByz.y*sByz.y;
    const float normA = sqrtf(n2fA + EPSQ);
    const float normB = sqrtf(n2fB + EPSQ);
    const float tgtA = bo * normA + ao + bi;
    const float tgtB = bo * normB + ao + bi;
    const float actA = rcp_fast(1.f + __builtin_amdgcn_exp2f(-tgtA * LOG2E));
    const float actB = rcp_fast(1.f + __builtin_amdgcn_exp2f(-tgtB * LOG2E));
    float4 ovA, ovB;
    ovA.x = oAwx.x * actA; ovA.y = oAwx.y * actA;
    ovA.z = oAyz.x * actA; ovA.w = oAyz.y * actA;
    ovB.x = oBwx.x * actB; ovB.y = oBwx.y * actB;
    ovB.z = oByz.x * actB; ovB.w = oByz.y * actB;
    const size_t obase = (size_t)blockIdx.x * 512 + tid;
    ((float4*)out)[obase]       = ovA;
    ((float4*)out)[obase + 256] = ovB;
}

extern "C" void kernel_launch(void* const* d_in, const int* in_sizes, int n_in,
                              void* d_out, int out_size, void* d_ws, size_t ws_size,
                              hipStream_t stream) {
    const float* x     = (const float*)d_in[0];
    const float* quats = (const float*)d_in[1];
    const float* scale = (const float*)d_in[2];
    const float* trans = (const float*)d_in[3];
    const float* bias  = (const float*)d_in[4];
    const float* beta  = (const float*)d_in[5];
    const float* alpha = (const float*)d_in[6];
    float* out = (float*)d_out;

    const int N = in_sizes[0] / 64;      // x is [N,16,4]
    caps_kernel<<<N / 32, 256, 0, stream>>>(x, quats, scale, trans, bias, beta, alpha, out);
}